// Round 1
// baseline (541.818 us; speedup 1.0000x reference)
//
#include <hip/hip_runtime.h>

#define NN 20000
#define FF 128
#define HH 128
#define LL 4
#define OO 64
#define EE 640000
#define NEG 0.2f

// ---------------- CSR build (dst-grouped, launch-invariant) ----------------

__global__ void k_init_counters(int* __restrict__ counters) {
    int i = blockIdx.x * 256 + threadIdx.x;
    if (i < NN) counters[i] = 1;  // self-loop pre-counted
}

__global__ void k_hist(const int* __restrict__ dst, int* __restrict__ counters) {
    int e = blockIdx.x * 256 + threadIdx.x;
    if (e < EE) atomicAdd(&counters[dst[e]], 1);
}

// single block, 1024 threads: exclusive scan of counters -> row_off; init cursor;
// place self-loop edge first in each segment.
__global__ void k_scan(const int* __restrict__ counters, int* __restrict__ row_off,
                       int* __restrict__ cursor, int* __restrict__ src_sorted) {
    __shared__ int part[1024];
    int t = threadIdx.x;
    const int CH = (NN + 1023) / 1024;  // 20
    int base = t * CH;
    int sum = 0;
    for (int i = 0; i < CH; i++) {
        int idx = base + i;
        if (idx < NN) sum += counters[idx];
    }
    part[t] = sum;
    __syncthreads();
    for (int off = 1; off < 1024; off <<= 1) {
        int v = (t >= off) ? part[t - off] : 0;
        __syncthreads();
        part[t] += v;
        __syncthreads();
    }
    int prefix = (t == 0) ? 0 : part[t - 1];
    for (int i = 0; i < CH; i++) {
        int idx = base + i;
        if (idx < NN) {
            int c = counters[idx];
            row_off[idx] = prefix;
            cursor[idx] = prefix + 1;     // slot 0 taken by self-loop
            src_sorted[prefix] = idx;     // self-loop edge
            prefix += c;
        }
    }
    if (t == 1023) row_off[NN] = part[1023];
}

__global__ void k_scatter(const int* __restrict__ src, const int* __restrict__ dst,
                          int* __restrict__ cursor, int* __restrict__ src_sorted) {
    int e = blockIdx.x * 256 + threadIdx.x;
    if (e < EE) {
        int p = atomicAdd(&cursor[dst[e]], 1);
        src_sorted[p] = src[e];
    }
}

// ---------------- GEMM: C[N][NCOL] = A[N][128] @ W[128][NCOL] (+bias) ----------------
// block 256 threads, tile 64 rows x NCOL cols, K chunked by 32.

template <int NCOL, bool BIAS>
__global__ void k_gemm(const float* __restrict__ A, const float* __restrict__ W,
                       const float* __restrict__ bias, float* __restrict__ C) {
    constexpr int KB = 32;
    constexpr int CG = NCOL / 4;   // threads along cols
    constexpr int TR = 256 / CG;   // thread-rows
    constexpr int RPT = 64 / TR;   // rows per thread
    __shared__ float sA[64][KB];
    __shared__ float sW[KB][NCOL];

    int t = threadIdx.x;
    int row0 = blockIdx.x * 64;
    int cg = t % CG, tr = t / CG;
    int c0 = cg * 4;

    float acc[RPT][4] = {};

    for (int k0 = 0; k0 < 128; k0 += KB) {
        // stage A chunk: 64 x 32 floats
        for (int i = t; i < 64 * KB / 4; i += 256) {
            int r = (i * 4) / KB, kk = (i * 4) % KB;
            float4 v;
            if (row0 + r < NN)
                v = *(const float4*)&A[(size_t)(row0 + r) * 128 + k0 + kk];
            else
                v = make_float4(0.f, 0.f, 0.f, 0.f);
            *(float4*)&sA[r][kk] = v;
        }
        // stage W chunk: 32 x NCOL floats
        for (int i = t; i < KB * NCOL / 4; i += 256) {
            int r = (i * 4) / NCOL, c = (i * 4) % NCOL;
            *(float4*)&sW[r][c] = *(const float4*)&W[(size_t)(k0 + r) * NCOL + c];
        }
        __syncthreads();

        #pragma unroll
        for (int k = 0; k < KB; k++) {
            float wv[4];
            *(float4*)wv = *(const float4*)&sW[k][c0];
            #pragma unroll
            for (int r = 0; r < RPT; r++) {
                float av = sA[tr * RPT + r][k];
                acc[r][0] += av * wv[0];
                acc[r][1] += av * wv[1];
                acc[r][2] += av * wv[2];
                acc[r][3] += av * wv[3];
            }
        }
        __syncthreads();
    }

    #pragma unroll
    for (int r = 0; r < RPT; r++) {
        int row = row0 + tr * RPT + r;
        if (row < NN) {
            float4 v = make_float4(acc[r][0], acc[r][1], acc[r][2], acc[r][3]);
            if (BIAS) {
                v.x += bias[c0 + 0];
                v.y += bias[c0 + 1];
                v.z += bias[c0 + 2];
                v.w += bias[c0 + 3];
            }
            *(float4*)&C[(size_t)row * NCOL + c0] = v;
        }
    }
}

// ---------------- per-node attention scalars ----------------

__global__ void k_alphas(const float* __restrict__ z, const float* __restrict__ a_s,
                         const float* __restrict__ a_d, float* __restrict__ as_out,
                         float* __restrict__ ad_out) {
    int node = blockIdx.x * 4 + (threadIdx.x >> 6);
    int lane = threadIdx.x & 63;
    if (node >= NN) return;
    const float* zr = z + (size_t)node * HH;
    float z0 = zr[lane], z1 = zr[lane + 64];
    float s1 = z0 * a_s[lane] + z1 * a_s[lane + 64];
    float s2 = z0 * a_d[lane] + z1 * a_d[lane + 64];
    #pragma unroll
    for (int off = 32; off; off >>= 1) {
        s1 += __shfl_xor(s1, off);
        s2 += __shfl_xor(s2, off);
    }
    if (lane == 0) {
        as_out[node] = s1;
        ad_out[node] = s2;
    }
}

// ---------------- per-node softmax + aggregation (wave per node) ----------------

__global__ void k_aggregate(const float* __restrict__ z, const float* __restrict__ as,
                            const float* __restrict__ ad, const int* __restrict__ row_off,
                            const int* __restrict__ srcs, const float* __restrict__ bias,
                            float* __restrict__ out) {
    int node = blockIdx.x * 4 + (threadIdx.x >> 6);
    int lane = threadIdx.x & 63;
    if (node >= NN) return;
    int beg = row_off[node], end = row_off[node + 1];
    float adn = ad[node];

    // phase 1: segment max (lane-parallel over edges)
    float mx = -1e30f;
    for (int e = beg + lane; e < end; e += 64) {
        float l = as[srcs[e]] + adn;
        l = (l >= 0.f) ? l : NEG * l;
        mx = fmaxf(mx, l);
    }
    #pragma unroll
    for (int off = 32; off; off >>= 1) mx = fmaxf(mx, __shfl_xor(mx, off));

    // phase 2: serial over edges, lanes parallel over 128 channels
    float acc0 = 0.f, acc1 = 0.f, s = 0.f;
    for (int e = beg; e < end; e++) {
        int sn = srcs[e];
        float l = as[sn] + adn;              // broadcast load
        l = (l >= 0.f) ? l : NEG * l;
        float p = __expf(l - mx);
        s += p;
        const float* zr = z + (size_t)sn * HH;
        acc0 += p * zr[lane];
        acc1 += p * zr[lane + 64];
    }
    float inv = 1.f / (s + 1e-16f);
    float o0 = acc0 * inv + bias[lane];
    float o1 = acc1 * inv + bias[lane + 64];
    out[(size_t)node * HH + lane]      = fmaxf(o0, 0.f);
    out[(size_t)node * HH + lane + 64] = fmaxf(o1, 0.f);
}

// ---------------- launch ----------------

extern "C" void kernel_launch(void* const* d_in, const int* in_sizes, int n_in,
                              void* d_out, int out_size, void* d_ws, size_t ws_size,
                              hipStream_t stream) {
    const float* x      = (const float*)d_in[0];
    const int*   ei     = (const int*)d_in[1];
    const float* Ws     = (const float*)d_in[2];
    const float* attS   = (const float*)d_in[3];
    const float* attD   = (const float*)d_in[4];
    const float* biases = (const float*)d_in[5];
    const float* W_out  = (const float*)d_in[6];
    const float* b_out  = (const float*)d_in[7];
    float* out = (float*)d_out;

    const int* srcp = ei;
    const int* dstp = ei + EE;

    // workspace layout (16B-aligned slices)
    char* w = (char*)d_ws;
    auto take = [&](size_t bytes) {
        char* p = w;
        w += (bytes + 15) & ~(size_t)15;
        return p;
    };
    float* zbuf       = (float*)take((size_t)NN * HH * 4);
    float* hbuf       = (float*)take((size_t)NN * HH * 4);
    float* as_v       = (float*)take((size_t)NN * 4);
    float* ad_v       = (float*)take((size_t)NN * 4);
    int*   counters   = (int*)take((size_t)NN * 4);
    int*   row_off    = (int*)take((size_t)(NN + 1) * 4);
    int*   cursor     = (int*)take((size_t)NN * 4);
    int*   src_sorted = (int*)take((size_t)(EE + NN) * 4);

    // CSR build
    k_init_counters<<<(NN + 255) / 256, 256, 0, stream>>>(counters);
    k_hist<<<(EE + 255) / 256, 256, 0, stream>>>(dstp, counters);
    k_scan<<<1, 1024, 0, stream>>>(counters, row_off, cursor, src_sorted);
    k_scatter<<<(EE + 255) / 256, 256, 0, stream>>>(srcp, dstp, cursor, src_sorted);

    const int gemm_blocks = (NN + 63) / 64;
    const int node_blocks = (NN + 3) / 4;

    for (int l = 0; l < LL; l++) {
        const float* hin = (l == 0) ? x : hbuf;
        k_gemm<HH, false><<<gemm_blocks, 256, 0, stream>>>(hin, Ws + (size_t)l * FF * HH,
                                                           nullptr, zbuf);
        k_alphas<<<node_blocks, 256, 0, stream>>>(zbuf, attS + l * HH, attD + l * HH,
                                                  as_v, ad_v);
        k_aggregate<<<node_blocks, 256, 0, stream>>>(zbuf, as_v, ad_v, row_off, src_sorted,
                                                     biases + l * HH, hbuf);
    }

    k_gemm<OO, true><<<gemm_blocks, 256, 0, stream>>>(hbuf, W_out, b_out, out);
}

// Round 2
// 399.658 us; speedup vs baseline: 1.3557x; 1.3557x over previous
//
#include <hip/hip_runtime.h>

#define NN 20000
#define FF 128
#define HH 128
#define LL 4
#define OO 64
#define EE 640000
#define NEG 0.2f

// ---------------- CSR build (dst-grouped, launch-invariant) ----------------

__global__ void k_init_counters(int* __restrict__ counters) {
    int i = blockIdx.x * 256 + threadIdx.x;
    if (i < NN) counters[i] = 1;  // self-loop pre-counted
}

__global__ void k_hist(const int* __restrict__ dst, int* __restrict__ counters) {
    int e = blockIdx.x * 256 + threadIdx.x;
    if (e < EE) atomicAdd(&counters[dst[e]], 1);
}

// single block, 1024 threads: exclusive scan of counters -> row_off; init cursor;
// place self-loop edge first in each segment.
__global__ void k_scan(const int* __restrict__ counters, int* __restrict__ row_off,
                       int* __restrict__ cursor, int* __restrict__ src_sorted) {
    __shared__ int part[1024];
    int t = threadIdx.x;
    const int CH = (NN + 1023) / 1024;  // 20
    int base = t * CH;
    int sum = 0;
    for (int i = 0; i < CH; i++) {
        int idx = base + i;
        if (idx < NN) sum += counters[idx];
    }
    part[t] = sum;
    __syncthreads();
    for (int off = 1; off < 1024; off <<= 1) {
        int v = (t >= off) ? part[t - off] : 0;
        __syncthreads();
        part[t] += v;
        __syncthreads();
    }
    int prefix = (t == 0) ? 0 : part[t - 1];
    for (int i = 0; i < CH; i++) {
        int idx = base + i;
        if (idx < NN) {
            int c = counters[idx];
            row_off[idx] = prefix;
            cursor[idx] = prefix + 1;     // slot 0 taken by self-loop
            src_sorted[prefix] = idx;     // self-loop edge
            prefix += c;
        }
    }
    if (t == 1023) row_off[NN] = part[1023];
}

__global__ void k_scatter(const int* __restrict__ src, const int* __restrict__ dst,
                          int* __restrict__ cursor, int* __restrict__ src_sorted) {
    int e = blockIdx.x * 256 + threadIdx.x;
    if (e < EE) {
        int p = atomicAdd(&cursor[dst[e]], 1);
        src_sorted[p] = src[e];
    }
}

// ---------------- GEMM: C[N][NCOL] = A[N][128] @ W[128][NCOL] (+bias) ----------------
// block 256 threads, tile 64 rows x NCOL cols, K chunked by 32.

template <int NCOL, bool BIAS>
__global__ void k_gemm(const float* __restrict__ A, const float* __restrict__ W,
                       const float* __restrict__ bias, float* __restrict__ C) {
    constexpr int KB = 32;
    constexpr int CG = NCOL / 4;   // threads along cols
    constexpr int TR = 256 / CG;   // thread-rows
    constexpr int RPT = 64 / TR;   // rows per thread
    __shared__ float sA[64][KB];
    __shared__ float sW[KB][NCOL];

    int t = threadIdx.x;
    int row0 = blockIdx.x * 64;
    int cg = t % CG, tr = t / CG;
    int c0 = cg * 4;

    float acc[RPT][4] = {};

    for (int k0 = 0; k0 < 128; k0 += KB) {
        // stage A chunk: 64 x 32 floats
        for (int i = t; i < 64 * KB / 4; i += 256) {
            int r = (i * 4) / KB, kk = (i * 4) % KB;
            float4 v;
            if (row0 + r < NN)
                v = *(const float4*)&A[(size_t)(row0 + r) * 128 + k0 + kk];
            else
                v = make_float4(0.f, 0.f, 0.f, 0.f);
            *(float4*)&sA[r][kk] = v;
        }
        // stage W chunk: 32 x NCOL floats
        for (int i = t; i < KB * NCOL / 4; i += 256) {
            int r = (i * 4) / NCOL, c = (i * 4) % NCOL;
            *(float4*)&sW[r][c] = *(const float4*)&W[(size_t)(k0 + r) * NCOL + c];
        }
        __syncthreads();

        #pragma unroll
        for (int k = 0; k < KB; k++) {
            float wv[4];
            *(float4*)wv = *(const float4*)&sW[k][c0];
            #pragma unroll
            for (int r = 0; r < RPT; r++) {
                float av = sA[tr * RPT + r][k];
                acc[r][0] += av * wv[0];
                acc[r][1] += av * wv[1];
                acc[r][2] += av * wv[2];
                acc[r][3] += av * wv[3];
            }
        }
        __syncthreads();
    }

    #pragma unroll
    for (int r = 0; r < RPT; r++) {
        int row = row0 + tr * RPT + r;
        if (row < NN) {
            float4 v = make_float4(acc[r][0], acc[r][1], acc[r][2], acc[r][3]);
            if (BIAS) {
                v.x += bias[c0 + 0];
                v.y += bias[c0 + 1];
                v.z += bias[c0 + 2];
                v.w += bias[c0 + 3];
            }
            *(float4*)&C[(size_t)row * NCOL + c0] = v;
        }
    }
}

// ---------------- per-node attention scalars ----------------

__global__ void k_alphas(const float* __restrict__ z, const float* __restrict__ a_s,
                         const float* __restrict__ a_d, float* __restrict__ as_out,
                         float* __restrict__ ad_out) {
    int node = blockIdx.x * 4 + (threadIdx.x >> 6);
    int lane = threadIdx.x & 63;
    if (node >= NN) return;
    const float* zr = z + (size_t)node * HH;
    float z0 = zr[lane], z1 = zr[lane + 64];
    float s1 = z0 * a_s[lane] + z1 * a_s[lane + 64];
    float s2 = z0 * a_d[lane] + z1 * a_d[lane + 64];
    #pragma unroll
    for (int off = 32; off; off >>= 1) {
        s1 += __shfl_xor(s1, off);
        s2 += __shfl_xor(s2, off);
    }
    if (lane == 0) {
        as_out[node] = s1;
        ad_out[node] = s2;
    }
}

// ---------------- per-node softmax + aggregation (wave per node) ----------------
// phase 2: 2 lane-groups x 2-deep unroll = 4 edges in flight, float4 channel loads

__global__ void k_aggregate(const float* __restrict__ z, const float* __restrict__ as,
                            const float* __restrict__ ad, const int* __restrict__ row_off,
                            const int* __restrict__ srcs, const float* __restrict__ bias,
                            float* __restrict__ out) {
    int node = blockIdx.x * 4 + (threadIdx.x >> 6);
    int lane = threadIdx.x & 63;
    if (node >= NN) return;
    int beg = row_off[node], end = row_off[node + 1];
    float adn = ad[node];

    // phase 1: exact segment max (lanes parallel over edges)
    float mx = -1e30f;
    for (int e = beg + lane; e < end; e += 64) {
        float l = as[srcs[e]] + adn;
        l = (l >= 0.f) ? l : NEG * l;
        mx = fmaxf(mx, l);
    }
    #pragma unroll
    for (int off = 32; off; off >>= 1) mx = fmaxf(mx, __shfl_xor(mx, off));

    // phase 2: group g handles edges beg+g, beg+g+2, ...; lane covers 4 channels
    int g = lane >> 5, cl = lane & 31;
    const float4* zb = (const float4*)z;  // row stride = 32 float4
    float4 acc = make_float4(0.f, 0.f, 0.f, 0.f);
    float s = 0.f;
    int e = beg + g;
    for (; e + 2 < end; e += 4) {  // unroll-2: edges e and e+2
        int s0 = srcs[e], s1 = srcs[e + 2];
        float l0 = as[s0] + adn; l0 = (l0 >= 0.f) ? l0 : NEG * l0;
        float l1 = as[s1] + adn; l1 = (l1 >= 0.f) ? l1 : NEG * l1;
        float4 z0 = zb[(size_t)s0 * 32 + cl];
        float4 z1 = zb[(size_t)s1 * 32 + cl];
        float p0 = __expf(l0 - mx), p1 = __expf(l1 - mx);
        s += p0 + p1;
        acc.x += p0 * z0.x + p1 * z1.x;
        acc.y += p0 * z0.y + p1 * z1.y;
        acc.z += p0 * z0.z + p1 * z1.z;
        acc.w += p0 * z0.w + p1 * z1.w;
    }
    for (; e < end; e += 2) {  // tail
        int s0 = srcs[e];
        float l0 = as[s0] + adn; l0 = (l0 >= 0.f) ? l0 : NEG * l0;
        float4 z0 = zb[(size_t)s0 * 32 + cl];
        float p0 = __expf(l0 - mx);
        s += p0;
        acc.x += p0 * z0.x;
        acc.y += p0 * z0.y;
        acc.z += p0 * z0.z;
        acc.w += p0 * z0.w;
    }

    // cross-group combine (lane ^ 32)
    acc.x += __shfl_xor(acc.x, 32);
    acc.y += __shfl_xor(acc.y, 32);
    acc.z += __shfl_xor(acc.z, 32);
    acc.w += __shfl_xor(acc.w, 32);
    s     += __shfl_xor(s, 32);

    if (g == 0) {
        float inv = 1.f / (s + 1e-16f);
        float4 b = ((const float4*)bias)[cl];
        float4 o;
        o.x = fmaxf(acc.x * inv + b.x, 0.f);
        o.y = fmaxf(acc.y * inv + b.y, 0.f);
        o.z = fmaxf(acc.z * inv + b.z, 0.f);
        o.w = fmaxf(acc.w * inv + b.w, 0.f);
        ((float4*)out)[(size_t)node * 32 + cl] = o;
    }
}

// ---------------- launch ----------------

extern "C" void kernel_launch(void* const* d_in, const int* in_sizes, int n_in,
                              void* d_out, int out_size, void* d_ws, size_t ws_size,
                              hipStream_t stream) {
    const float* x      = (const float*)d_in[0];
    const int*   ei     = (const int*)d_in[1];
    const float* Ws     = (const float*)d_in[2];
    const float* attS   = (const float*)d_in[3];
    const float* attD   = (const float*)d_in[4];
    const float* biases = (const float*)d_in[5];
    const float* W_out  = (const float*)d_in[6];
    const float* b_out  = (const float*)d_in[7];
    float* out = (float*)d_out;

    const int* srcp = ei;
    const int* dstp = ei + EE;

    // workspace layout (16B-aligned slices)
    char* w = (char*)d_ws;
    auto take = [&](size_t bytes) {
        char* p = w;
        w += (bytes + 15) & ~(size_t)15;
        return p;
    };
    float* zbuf       = (float*)take((size_t)NN * HH * 4);
    float* hbuf       = (float*)take((size_t)NN * HH * 4);
    float* as_v       = (float*)take((size_t)NN * 4);
    float* ad_v       = (float*)take((size_t)NN * 4);
    int*   counters   = (int*)take((size_t)NN * 4);
    int*   row_off    = (int*)take((size_t)(NN + 1) * 4);
    int*   cursor     = (int*)take((size_t)NN * 4);
    int*   src_sorted = (int*)take((size_t)(EE + NN) * 4);

    // CSR build
    k_init_counters<<<(NN + 255) / 256, 256, 0, stream>>>(counters);
    k_hist<<<(EE + 255) / 256, 256, 0, stream>>>(dstp, counters);
    k_scan<<<1, 1024, 0, stream>>>(counters, row_off, cursor, src_sorted);
    k_scatter<<<(EE + 255) / 256, 256, 0, stream>>>(srcp, dstp, cursor, src_sorted);

    const int gemm_blocks = (NN + 63) / 64;
    const int node_blocks = (NN + 3) / 4;

    for (int l = 0; l < LL; l++) {
        const float* hin = (l == 0) ? x : hbuf;
        k_gemm<HH, false><<<gemm_blocks, 256, 0, stream>>>(hin, Ws + (size_t)l * FF * HH,
                                                           nullptr, zbuf);
        k_alphas<<<node_blocks, 256, 0, stream>>>(zbuf, attS + l * HH, attD + l * HH,
                                                  as_v, ad_v);
        k_aggregate<<<node_blocks, 256, 0, stream>>>(zbuf, as_v, ad_v, row_off, src_sorted,
                                                     biases + l * HH, hbuf);
    }

    k_gemm<OO, true><<<gemm_blocks, 256, 0, stream>>>(hbuf, W_out, b_out, out);
}

// Round 3
// 340.324 us; speedup vs baseline: 1.5921x; 1.1743x over previous
//
#include <hip/hip_runtime.h>

#define NN 20000
#define FF 128
#define HH 128
#define LL 4
#define OO 64
#define EE 640000
#define NEG 0.2f
#define NB ((NN + 255) / 256)   // 79 scan blocks

// ---------------- CSR build (dst-grouped, launch-invariant) ----------------

__global__ void k_init_counters(int* __restrict__ counters) {
    int i = blockIdx.x * 256 + threadIdx.x;
    if (i < NN) counters[i] = 1;  // self-loop pre-counted
}

__global__ void k_hist(const int* __restrict__ dst, int* __restrict__ counters) {
    int e = blockIdx.x * 256 + threadIdx.x;
    if (e < EE) atomicAdd(&counters[dst[e]], 1);
}

// stage 1: per-block sums of counters
__global__ void k_partial(const int* __restrict__ counters, int* __restrict__ partials) {
    __shared__ int ws[4];
    int t = threadIdx.x;
    int i = blockIdx.x * 256 + t;
    int c = (i < NN) ? counters[i] : 0;
    #pragma unroll
    for (int off = 32; off; off >>= 1) c += __shfl_xor(c, off);
    if ((t & 63) == 0) ws[t >> 6] = c;
    __syncthreads();
    if (t == 0) partials[blockIdx.x] = ws[0] + ws[1] + ws[2] + ws[3];
}

// stage 2: exclusive scan of NB partials (single block, 128 threads)
__global__ void k_scan_small(const int* __restrict__ partials, int* __restrict__ offsets) {
    __shared__ int sp[128];
    int t = threadIdx.x;
    int v = (t < NB) ? partials[t] : 0;
    sp[t] = v;
    __syncthreads();
    for (int off = 1; off < 128; off <<= 1) {
        int u = (t >= off) ? sp[t - off] : 0;
        __syncthreads();
        sp[t] += u;
        __syncthreads();
    }
    if (t < NB) offsets[t] = sp[t] - v;  // exclusive
}

// stage 3: intra-block exclusive scan + emit row_off / cursor / self-loop
__global__ void k_apply(const int* __restrict__ counters, const int* __restrict__ offsets,
                        int* __restrict__ row_off, int* __restrict__ cursor,
                        int* __restrict__ src_sorted) {
    __shared__ int sc[256];
    int t = threadIdx.x;
    int i = blockIdx.x * 256 + t;
    int c = (i < NN) ? counters[i] : 0;
    sc[t] = c;
    __syncthreads();
    for (int off = 1; off < 256; off <<= 1) {
        int u = (t >= off) ? sc[t - off] : 0;
        __syncthreads();
        sc[t] += u;
        __syncthreads();
    }
    int incl = sc[t];
    int base = offsets[blockIdx.x];
    if (i < NN) {
        int excl = base + incl - c;
        row_off[i] = excl;
        cursor[i] = excl + 1;       // slot 0 taken by self-loop
        src_sorted[excl] = i;       // self-loop edge first
        if (i == NN - 1) row_off[NN] = base + incl;
    }
}

__global__ void k_scatter(const int* __restrict__ src, const int* __restrict__ dst,
                          int* __restrict__ cursor, int* __restrict__ src_sorted) {
    int e = blockIdx.x * 256 + threadIdx.x;
    if (e < EE) {
        int p = atomicAdd(&cursor[dst[e]], 1);
        src_sorted[p] = src[e];
    }
}

// ---------------- GEMM: C[N][NCOL] = A[N][128] @ W[128][NCOL] (+bias) ----------------
// block 256 threads, tile 64 rows x NCOL cols, K chunked by 32.
// ALPHAS: fused epilogue computing as_out[row] = C_row . a_s, ad_out likewise.

template <int NCOL, bool BIAS, bool ALPHAS>
__global__ void k_gemm(const float* __restrict__ A, const float* __restrict__ W,
                       const float* __restrict__ bias, float* __restrict__ C,
                       const float* __restrict__ a_s, const float* __restrict__ a_d,
                       float* __restrict__ as_out, float* __restrict__ ad_out) {
    constexpr int KB = 32;
    constexpr int CG = NCOL / 4;   // threads along cols
    constexpr int TR = 256 / CG;   // thread-rows
    constexpr int RPT = 64 / TR;   // rows per thread
    __shared__ float sA[64][KB];
    __shared__ float sW[KB][NCOL];

    int t = threadIdx.x;
    int row0 = blockIdx.x * 64;
    int cg = t % CG, tr = t / CG;
    int c0 = cg * 4;

    float acc[RPT][4] = {};

    for (int k0 = 0; k0 < 128; k0 += KB) {
        for (int i = t; i < 64 * KB / 4; i += 256) {
            int r = (i * 4) / KB, kk = (i * 4) % KB;
            float4 v;
            if (row0 + r < NN)
                v = *(const float4*)&A[(size_t)(row0 + r) * 128 + k0 + kk];
            else
                v = make_float4(0.f, 0.f, 0.f, 0.f);
            *(float4*)&sA[r][kk] = v;
        }
        for (int i = t; i < KB * NCOL / 4; i += 256) {
            int r = (i * 4) / NCOL, c = (i * 4) % NCOL;
            *(float4*)&sW[r][c] = *(const float4*)&W[(size_t)(k0 + r) * NCOL + c];
        }
        __syncthreads();

        #pragma unroll
        for (int k = 0; k < KB; k++) {
            float wv[4];
            *(float4*)wv = *(const float4*)&sW[k][c0];
            #pragma unroll
            for (int r = 0; r < RPT; r++) {
                float av = sA[tr * RPT + r][k];
                acc[r][0] += av * wv[0];
                acc[r][1] += av * wv[1];
                acc[r][2] += av * wv[2];
                acc[r][3] += av * wv[3];
            }
        }
        __syncthreads();
    }

    #pragma unroll
    for (int r = 0; r < RPT; r++) {
        int row = row0 + tr * RPT + r;
        if (row < NN) {
            float4 v = make_float4(acc[r][0], acc[r][1], acc[r][2], acc[r][3]);
            if (BIAS) {
                v.x += bias[c0 + 0];
                v.y += bias[c0 + 1];
                v.z += bias[c0 + 2];
                v.w += bias[c0 + 3];
            }
            *(float4*)&C[(size_t)row * NCOL + c0] = v;
        }
    }

    if constexpr (ALPHAS) {
        // dot each row with a_s / a_d; reduce across the CG(=32) col-lanes
        float4 asv = *(const float4*)&a_s[c0];
        float4 adv = *(const float4*)&a_d[c0];
        #pragma unroll
        for (int r = 0; r < RPT; r++) {
            float ps = acc[r][0] * asv.x + acc[r][1] * asv.y +
                       acc[r][2] * asv.z + acc[r][3] * asv.w;
            float pd = acc[r][0] * adv.x + acc[r][1] * adv.y +
                       acc[r][2] * adv.z + acc[r][3] * adv.w;
            #pragma unroll
            for (int off = 16; off; off >>= 1) {
                ps += __shfl_xor(ps, off);
                pd += __shfl_xor(pd, off);
            }
            int row = row0 + tr * RPT + r;
            if (cg == 0 && row < NN) {
                as_out[row] = ps;
                ad_out[row] = pd;
            }
        }
    }
}

// ---------------- per-node softmax + aggregation (wave per node) ----------------
// phase 2: 2 lane-groups x 4-deep unroll = 8 edges in flight, float4 channel loads

__global__ void k_aggregate(const float* __restrict__ z, const float* __restrict__ as,
                            const float* __restrict__ ad, const int* __restrict__ row_off,
                            const int* __restrict__ srcs, const float* __restrict__ bias,
                            float* __restrict__ out) {
    int node = blockIdx.x * 4 + (threadIdx.x >> 6);
    int lane = threadIdx.x & 63;
    if (node >= NN) return;
    int beg = row_off[node], end = row_off[node + 1];
    float adn = ad[node];

    // phase 1: exact segment max (lanes parallel over edges)
    float mx = -1e30f;
    for (int e = beg + lane; e < end; e += 64) {
        float l = as[srcs[e]] + adn;
        l = (l >= 0.f) ? l : NEG * l;
        mx = fmaxf(mx, l);
    }
    #pragma unroll
    for (int off = 32; off; off >>= 1) mx = fmaxf(mx, __shfl_xor(mx, off));

    // phase 2: group g handles edges beg+g, beg+g+2, ...; lane covers 4 channels
    int g = lane >> 5, cl = lane & 31;
    const float4* zb = (const float4*)z;  // row stride = 32 float4
    float4 acc = make_float4(0.f, 0.f, 0.f, 0.f);
    float s = 0.f;
    int e = beg + g;
    for (; e + 6 < end; e += 8) {  // 4 edges per group per iter
        int s0 = srcs[e], s1 = srcs[e + 2], s2 = srcs[e + 4], s3 = srcs[e + 6];
        float l0 = as[s0] + adn; l0 = (l0 >= 0.f) ? l0 : NEG * l0;
        float l1 = as[s1] + adn; l1 = (l1 >= 0.f) ? l1 : NEG * l1;
        float l2 = as[s2] + adn; l2 = (l2 >= 0.f) ? l2 : NEG * l2;
        float l3 = as[s3] + adn; l3 = (l3 >= 0.f) ? l3 : NEG * l3;
        float4 z0 = zb[(size_t)s0 * 32 + cl];
        float4 z1 = zb[(size_t)s1 * 32 + cl];
        float4 z2 = zb[(size_t)s2 * 32 + cl];
        float4 z3 = zb[(size_t)s3 * 32 + cl];
        float p0 = __expf(l0 - mx), p1 = __expf(l1 - mx);
        float p2 = __expf(l2 - mx), p3 = __expf(l3 - mx);
        s += (p0 + p1) + (p2 + p3);
        acc.x += p0 * z0.x + p1 * z1.x + p2 * z2.x + p3 * z3.x;
        acc.y += p0 * z0.y + p1 * z1.y + p2 * z2.y + p3 * z3.y;
        acc.z += p0 * z0.z + p1 * z1.z + p2 * z2.z + p3 * z3.z;
        acc.w += p0 * z0.w + p1 * z1.w + p2 * z2.w + p3 * z3.w;
    }
    for (; e < end; e += 2) {  // tail
        int s0 = srcs[e];
        float l0 = as[s0] + adn; l0 = (l0 >= 0.f) ? l0 : NEG * l0;
        float4 z0 = zb[(size_t)s0 * 32 + cl];
        float p0 = __expf(l0 - mx);
        s += p0;
        acc.x += p0 * z0.x;
        acc.y += p0 * z0.y;
        acc.z += p0 * z0.z;
        acc.w += p0 * z0.w;
    }

    // cross-group combine (lane ^ 32)
    acc.x += __shfl_xor(acc.x, 32);
    acc.y += __shfl_xor(acc.y, 32);
    acc.z += __shfl_xor(acc.z, 32);
    acc.w += __shfl_xor(acc.w, 32);
    s     += __shfl_xor(s, 32);

    if (g == 0) {
        float inv = 1.f / (s + 1e-16f);
        float4 b = ((const float4*)bias)[cl];
        float4 o;
        o.x = fmaxf(acc.x * inv + b.x, 0.f);
        o.y = fmaxf(acc.y * inv + b.y, 0.f);
        o.z = fmaxf(acc.z * inv + b.z, 0.f);
        o.w = fmaxf(acc.w * inv + b.w, 0.f);
        ((float4*)out)[(size_t)node * 32 + cl] = o;
    }
}

// ---------------- launch ----------------

extern "C" void kernel_launch(void* const* d_in, const int* in_sizes, int n_in,
                              void* d_out, int out_size, void* d_ws, size_t ws_size,
                              hipStream_t stream) {
    const float* x      = (const float*)d_in[0];
    const int*   ei     = (const int*)d_in[1];
    const float* Ws     = (const float*)d_in[2];
    const float* attS   = (const float*)d_in[3];
    const float* attD   = (const float*)d_in[4];
    const float* biases = (const float*)d_in[5];
    const float* W_out  = (const float*)d_in[6];
    const float* b_out  = (const float*)d_in[7];
    float* out = (float*)d_out;

    const int* srcp = ei;
    const int* dstp = ei + EE;

    // workspace layout (16B-aligned slices)
    char* w = (char*)d_ws;
    auto take = [&](size_t bytes) {
        char* p = w;
        w += (bytes + 15) & ~(size_t)15;
        return p;
    };
    float* zbuf       = (float*)take((size_t)NN * HH * 4);
    float* hbuf       = (float*)take((size_t)NN * HH * 4);
    float* as_v       = (float*)take((size_t)NN * 4);
    float* ad_v       = (float*)take((size_t)NN * 4);
    int*   counters   = (int*)take((size_t)NN * 4);
    int*   row_off    = (int*)take((size_t)(NN + 1) * 4);
    int*   cursor     = (int*)take((size_t)NN * 4);
    int*   src_sorted = (int*)take((size_t)(EE + NN) * 4);
    int*   partials   = (int*)take((size_t)NB * 4);
    int*   offsets    = (int*)take((size_t)NB * 4);

    // CSR build
    k_init_counters<<<(NN + 255) / 256, 256, 0, stream>>>(counters);
    k_hist<<<(EE + 255) / 256, 256, 0, stream>>>(dstp, counters);
    k_partial<<<NB, 256, 0, stream>>>(counters, partials);
    k_scan_small<<<1, 128, 0, stream>>>(partials, offsets);
    k_apply<<<NB, 256, 0, stream>>>(counters, offsets, row_off, cursor, src_sorted);
    k_scatter<<<(EE + 255) / 256, 256, 0, stream>>>(srcp, dstp, cursor, src_sorted);

    const int gemm_blocks = (NN + 63) / 64;
    const int node_blocks = (NN + 3) / 4;

    for (int l = 0; l < LL; l++) {
        const float* hin = (l == 0) ? x : hbuf;
        k_gemm<HH, false, true><<<gemm_blocks, 256, 0, stream>>>(
            hin, Ws + (size_t)l * FF * HH, nullptr, zbuf,
            attS + l * HH, attD + l * HH, as_v, ad_v);
        k_aggregate<<<node_blocks, 256, 0, stream>>>(zbuf, as_v, ad_v, row_off, src_sorted,
                                                     biases + l * HH, hbuf);
    }

    k_gemm<OO, true, false><<<gemm_blocks, 256, 0, stream>>>(
        hbuf, W_out, b_out, out, nullptr, nullptr, nullptr, nullptr);
}